// Round 1
// baseline (1371.543 us; speedup 1.0000x reference)
//
#include <hip/hip_runtime.h>
#include <hip/hip_bf16.h>

#define NU_ 100000
#define NV_ 50000
#define NE_ 500000
#define EMB 128

typedef unsigned short u16;
typedef unsigned int u32;
typedef __attribute__((ext_vector_type(8))) short short8x;
typedef __attribute__((ext_vector_type(4))) float f32x4;

__device__ __forceinline__ float bf2f(u16 u) {
    union { u32 i; float f; } c; c.i = ((u32)u) << 16; return c.f;
}
__device__ __forceinline__ u16 f2bf(float f) {
    union { float f; u32 i; } c; c.f = f;
    u32 r = c.i + 0x7fffu + ((c.i >> 16) & 1u);
    return (u16)(r >> 16);
}

// ---------------------------------------------------------------------------
// Kernel 0: convert weights fp32 [K][128] -> bf16 transposed [128][K]
// ---------------------------------------------------------------------------
__global__ void convert_weights_kernel(
    const float* __restrict__ Wl, const float* __restrict__ We,
    const float* __restrict__ Wr, const float* __restrict__ Wj,
    const float* __restrict__ Wm,
    u16* __restrict__ wtl, u16* __restrict__ wte, u16* __restrict__ wtr,
    u16* __restrict__ wtj, u16* __restrict__ wtm)
{
    int b = blockIdx.x;
    const float* src; u16* dst; int K;
    if (b == 0)      { src = Wl; dst = wtl; K = 128; }
    else if (b == 1) { src = We; dst = wte; K = 128; }
    else if (b == 2) { src = Wr; dst = wtr; K = 128; }
    else if (b == 3) { src = Wj; dst = wtj; K = 128; }
    else             { src = Wm; dst = wtm; K = 256; }
    int total = K * 128;
    for (int i = threadIdx.x; i < total; i += blockDim.x) {
        int n = i / K, k = i - n * K;
        dst[i] = f2bf(src[(size_t)k * 128 + n]);   // Wt[n][k] = W[k][n]
    }
}

// ---------------------------------------------------------------------------
// Kernel 1: Y_bf16[N,128] = LN(X_f32; g,b) @ W (+bias).  64 rows per block.
// ---------------------------------------------------------------------------
__global__ __launch_bounds__(256) void ln_linear_kernel(
    const float* __restrict__ X, int Nrows,
    const float* __restrict__ g, const float* __restrict__ b,
    const u16* __restrict__ Wt, const float* __restrict__ bias,
    u16* __restrict__ Y)
{
    __shared__ __align__(16) u16 Asm[64][136];
    const int lane = threadIdx.x & 63, wv = threadIdx.x >> 6;
    const int ch = lane & 15, sub = lane >> 4;
    const int m0 = blockIdx.x * 64;
    const int rbase = wv * 16;

    float gv[8], bv[8];
#pragma unroll
    for (int j = 0; j < 8; ++j) { gv[j] = g[ch * 8 + j]; bv[j] = b[ch * 8 + j]; }

    // Phase 1: LN -> bf16 tile in LDS
    for (int it = 0; it < 4; ++it) {
        int rl = rbase + it * 4 + sub;
        int row = m0 + rl;
        int rowc = row < Nrows ? row : Nrows - 1;
        const float* xr = X + (size_t)rowc * EMB + ch * 8;
        float4 a0 = *(const float4*)xr;
        float4 a1 = *(const float4*)(xr + 4);
        float x[8] = {a0.x, a0.y, a0.z, a0.w, a1.x, a1.y, a1.z, a1.w};
        float s = 0.f, ss = 0.f;
#pragma unroll
        for (int j = 0; j < 8; ++j) { s += x[j]; ss += x[j] * x[j]; }
#pragma unroll
        for (int m = 1; m < 16; m <<= 1) { s += __shfl_xor(s, m, 64); ss += __shfl_xor(ss, m, 64); }
        float mu = s * (1.0f / EMB);
        float rstd = rsqrtf(ss * (1.0f / EMB) - mu * mu + 1e-5f);
        u16 o[8];
#pragma unroll
        for (int j = 0; j < 8; ++j) o[j] = f2bf((x[j] - mu) * rstd * gv[j] + bv[j]);
        uint4 pk;
        pk.x = (u32)o[0] | ((u32)o[1] << 16);
        pk.y = (u32)o[2] | ((u32)o[3] << 16);
        pk.z = (u32)o[4] | ((u32)o[5] << 16);
        pk.w = (u32)o[6] | ((u32)o[7] << 16);
        *(uint4*)&Asm[rl][ch * 8] = pk;
    }
    __syncthreads();

    // Phase 2: MFMA GEMM, wave wv handles rows rbase..rbase+15, all 128 cols
    short8x afr[4];
#pragma unroll
    for (int kt = 0; kt < 4; ++kt)
        afr[kt] = *(const short8x*)&Asm[rbase + ch][kt * 32 + sub * 8];

#pragma unroll
    for (int nt = 0; nt < 8; ++nt) {
        float bz = bias ? bias[nt * 16 + ch] : 0.f;
        f32x4 acc = {bz, bz, bz, bz};
#pragma unroll
        for (int kt = 0; kt < 4; ++kt) {
            short8x bfr = *(const short8x*)(Wt + (size_t)(nt * 16 + ch) * 128 + kt * 32 + sub * 8);
            acc = __builtin_amdgcn_mfma_f32_16x16x32_bf16(afr[kt], bfr, acc, 0, 0, 0);
        }
#pragma unroll
        for (int r = 0; r < 4; ++r) {
            int row = m0 + rbase + sub * 4 + r;
            if (row < Nrows) Y[(size_t)row * EMB + nt * 16 + ch] = f2bf(acc[r]);
        }
    }
}

// ---------------------------------------------------------------------------
// Kernel 2: edge pipeline. Per 64-edge block:
//   e_t = LN(edge_emb)@W_edge (in-kernel, not materialized)
//   j   = LN(relu(v_t[e_u] + e_t + c_t[e_v])) @ W_join + b_join
//   j   = LN(j); atomicAdd agg[seg[e]] += j
// ---------------------------------------------------------------------------
__global__ __launch_bounds__(256) void join_scatter_kernel(
    const float* __restrict__ Xe,
    const u16* __restrict__ v_t, const u16* __restrict__ c_t,
    const int* __restrict__ e_u, const int* __restrict__ e_v,
    const int* __restrict__ seg,
    const float* __restrict__ g_e, const float* __restrict__ b_e,
    const u16* __restrict__ Wt_e,
    const float* __restrict__ g1, const float* __restrict__ b1,
    const u16* __restrict__ Wt_j, const float* __restrict__ bias_j,
    const float* __restrict__ g2, const float* __restrict__ b2,
    float* __restrict__ agg)
{
    __shared__ __align__(16) u16 Asm[64][136];
    __shared__ __align__(16) u16 Esm[64][136];
    const int lane = threadIdx.x & 63, wv = threadIdx.x >> 6;
    const int ch = lane & 15, sub = lane >> 4;
    const int m0 = blockIdx.x * 64;
    const int rbase = wv * 16;

    float gev[8], bev[8];
#pragma unroll
    for (int j = 0; j < 8; ++j) { gev[j] = g_e[ch * 8 + j]; bev[j] = b_e[ch * 8 + j]; }

    // Phase A: LN(edge_emb) -> Asm
    for (int it = 0; it < 4; ++it) {
        int rl = rbase + it * 4 + sub;
        int edge = m0 + rl;
        int ec = edge < NE_ ? edge : NE_ - 1;
        const float* xr = Xe + (size_t)ec * EMB + ch * 8;
        float4 a0 = *(const float4*)xr;
        float4 a1 = *(const float4*)(xr + 4);
        float x[8] = {a0.x, a0.y, a0.z, a0.w, a1.x, a1.y, a1.z, a1.w};
        float s = 0.f, ss = 0.f;
#pragma unroll
        for (int j = 0; j < 8; ++j) { s += x[j]; ss += x[j] * x[j]; }
#pragma unroll
        for (int m = 1; m < 16; m <<= 1) { s += __shfl_xor(s, m, 64); ss += __shfl_xor(ss, m, 64); }
        float mu = s * (1.0f / EMB);
        float rstd = rsqrtf(ss * (1.0f / EMB) - mu * mu + 1e-5f);
        u16 o[8];
#pragma unroll
        for (int j = 0; j < 8; ++j) o[j] = f2bf((x[j] - mu) * rstd * gev[j] + bev[j]);
        uint4 pk;
        pk.x = (u32)o[0] | ((u32)o[1] << 16);
        pk.y = (u32)o[2] | ((u32)o[3] << 16);
        pk.z = (u32)o[4] | ((u32)o[5] << 16);
        pk.w = (u32)o[6] | ((u32)o[7] << 16);
        *(uint4*)&Asm[rl][ch * 8] = pk;
    }
    __syncthreads();

    // MFMA1: e_t tile = Asm @ Wt_e  -> Esm (bf16)
    {
        short8x afr[4];
#pragma unroll
        for (int kt = 0; kt < 4; ++kt)
            afr[kt] = *(const short8x*)&Asm[rbase + ch][kt * 32 + sub * 8];
#pragma unroll
        for (int nt = 0; nt < 8; ++nt) {
            f32x4 acc = {0.f, 0.f, 0.f, 0.f};
#pragma unroll
            for (int kt = 0; kt < 4; ++kt) {
                short8x bfr = *(const short8x*)(Wt_e + (size_t)(nt * 16 + ch) * 128 + kt * 32 + sub * 8);
                acc = __builtin_amdgcn_mfma_f32_16x16x32_bf16(afr[kt], bfr, acc, 0, 0, 0);
            }
#pragma unroll
            for (int r = 0; r < 4; ++r)
                Esm[rbase + sub * 4 + r][nt * 16 + ch] = f2bf(acc[r]);
        }
    }
    __syncthreads();

    // Phase C: gather + sum + relu + LN -> Asm (overwrite)
    float g1v[8], b1v[8];
#pragma unroll
    for (int j = 0; j < 8; ++j) { g1v[j] = g1[ch * 8 + j]; b1v[j] = b1[ch * 8 + j]; }
    for (int it = 0; it < 4; ++it) {
        int rl = rbase + it * 4 + sub;
        int edge = m0 + rl;
        int ec = edge < NE_ ? edge : NE_ - 1;
        int u = e_u[ec], vv = e_v[ec];
        uint4 vq = *(const uint4*)(v_t + (size_t)u * EMB + ch * 8);
        uint4 cq = *(const uint4*)(c_t + (size_t)vv * EMB + ch * 8);
        uint4 eq = *(const uint4*)&Esm[rl][ch * 8];
        u32 vw[4] = {vq.x, vq.y, vq.z, vq.w};
        u32 cw[4] = {cq.x, cq.y, cq.z, cq.w};
        u32 ew[4] = {eq.x, eq.y, eq.z, eq.w};
        float x[8];
#pragma unroll
        for (int j = 0; j < 4; ++j) {
            float v0 = bf2f((u16)(vw[j] & 0xffff)) + bf2f((u16)(cw[j] & 0xffff)) + bf2f((u16)(ew[j] & 0xffff));
            float v1 = bf2f((u16)(vw[j] >> 16)) + bf2f((u16)(cw[j] >> 16)) + bf2f((u16)(ew[j] >> 16));
            x[2 * j] = fmaxf(v0, 0.f);
            x[2 * j + 1] = fmaxf(v1, 0.f);
        }
        float s = 0.f, ss = 0.f;
#pragma unroll
        for (int j = 0; j < 8; ++j) { s += x[j]; ss += x[j] * x[j]; }
#pragma unroll
        for (int m = 1; m < 16; m <<= 1) { s += __shfl_xor(s, m, 64); ss += __shfl_xor(ss, m, 64); }
        float mu = s * (1.0f / EMB);
        float rstd = rsqrtf(ss * (1.0f / EMB) - mu * mu + 1e-5f);
        u16 o[8];
#pragma unroll
        for (int j = 0; j < 8; ++j) o[j] = f2bf((x[j] - mu) * rstd * g1v[j] + b1v[j]);
        uint4 pk;
        pk.x = (u32)o[0] | ((u32)o[1] << 16);
        pk.y = (u32)o[2] | ((u32)o[3] << 16);
        pk.z = (u32)o[4] | ((u32)o[5] << 16);
        pk.w = (u32)o[6] | ((u32)o[7] << 16);
        *(uint4*)&Asm[rl][ch * 8] = pk;
    }
    __syncthreads();

    // MFMA2: j = Asm @ Wt_j + b_join; then row-LN(g2,b2); scatter atomically
    short8x afr[4];
#pragma unroll
    for (int kt = 0; kt < 4; ++kt)
        afr[kt] = *(const short8x*)&Asm[rbase + ch][kt * 32 + sub * 8];

    f32x4 jacc[8];
#pragma unroll
    for (int nt = 0; nt < 8; ++nt) {
        float bz = bias_j[nt * 16 + ch];
        f32x4 acc = {bz, bz, bz, bz};
#pragma unroll
        for (int kt = 0; kt < 4; ++kt) {
            short8x bfr = *(const short8x*)(Wt_j + (size_t)(nt * 16 + ch) * 128 + kt * 32 + sub * 8);
            acc = __builtin_amdgcn_mfma_f32_16x16x32_bf16(afr[kt], bfr, acc, 0, 0, 0);
        }
        jacc[nt] = acc;
    }

    float g2v[8], b2v[8];
#pragma unroll
    for (int nt = 0; nt < 8; ++nt) { g2v[nt] = g2[nt * 16 + ch]; b2v[nt] = b2[nt * 16 + ch]; }

#pragma unroll
    for (int r = 0; r < 4; ++r) {
        float s = 0.f, ss = 0.f;
#pragma unroll
        for (int nt = 0; nt < 8; ++nt) { float v = jacc[nt][r]; s += v; ss += v * v; }
#pragma unroll
        for (int m = 1; m < 16; m <<= 1) { s += __shfl_xor(s, m, 64); ss += __shfl_xor(ss, m, 64); }
        float mu = s * (1.0f / EMB);
        float rstd = rsqrtf(ss * (1.0f / EMB) - mu * mu + 1e-5f);
        int edge = m0 + rbase + sub * 4 + r;
        if (edge < NE_) {
            int sg = seg[edge];
            float* dst = agg + (size_t)sg * EMB + ch;
#pragma unroll
            for (int nt = 0; nt < 8; ++nt) {
                float val = (jacc[nt][r] - mu) * rstd * g2v[nt] + b2v[nt];
                atomicAdd(dst + nt * 16, val);
            }
        }
    }
}

// ---------------------------------------------------------------------------
// Kernel 3: out = h + LN(relu([h, agg] @ W_merge + b_merge); g, bln)
// ---------------------------------------------------------------------------
__global__ __launch_bounds__(256) void merge_kernel(
    const u16* __restrict__ h, const float* __restrict__ agg, int Nrows,
    const u16* __restrict__ Wt_m,   // [128][256]
    const float* __restrict__ bias, const float* __restrict__ g,
    const float* __restrict__ bln,
    float* __restrict__ out)
{
    __shared__ __align__(16) u16 Asm[64][264];
    const int lane = threadIdx.x & 63, wv = threadIdx.x >> 6;
    const int ch = lane & 15, sub = lane >> 4;
    const int m0 = blockIdx.x * 64;
    const int rbase = wv * 16;

    // staging: cols 0..127 = h (bf16 copy), cols 128..255 = bf16(agg)
    for (int it = 0; it < 4; ++it) {
        int rl = rbase + it * 4 + sub;
        int row = m0 + rl;
        int rowc = row < Nrows ? row : Nrows - 1;
        uint4 hq = *(const uint4*)(h + (size_t)rowc * EMB + ch * 8);
        *(uint4*)&Asm[rl][ch * 8] = hq;
        const float* ar = agg + (size_t)rowc * EMB + ch * 8;
        float4 a0 = *(const float4*)ar;
        float4 a1 = *(const float4*)(ar + 4);
        float x[8] = {a0.x, a0.y, a0.z, a0.w, a1.x, a1.y, a1.z, a1.w};
        u16 o[8];
#pragma unroll
        for (int j = 0; j < 8; ++j) o[j] = f2bf(x[j]);
        uint4 pk;
        pk.x = (u32)o[0] | ((u32)o[1] << 16);
        pk.y = (u32)o[2] | ((u32)o[3] << 16);
        pk.z = (u32)o[4] | ((u32)o[5] << 16);
        pk.w = (u32)o[6] | ((u32)o[7] << 16);
        *(uint4*)&Asm[rl][128 + ch * 8] = pk;
    }
    __syncthreads();

    short8x afr[8];
#pragma unroll
    for (int kt = 0; kt < 8; ++kt)
        afr[kt] = *(const short8x*)&Asm[rbase + ch][kt * 32 + sub * 8];

    f32x4 macc[8];
#pragma unroll
    for (int nt = 0; nt < 8; ++nt) {
        float bz = bias[nt * 16 + ch];
        f32x4 acc = {bz, bz, bz, bz};
#pragma unroll
        for (int kt = 0; kt < 8; ++kt) {
            short8x bfr = *(const short8x*)(Wt_m + (size_t)(nt * 16 + ch) * 256 + kt * 32 + sub * 8);
            acc = __builtin_amdgcn_mfma_f32_16x16x32_bf16(afr[kt], bfr, acc, 0, 0, 0);
        }
        macc[nt] = acc;
    }

    float gm[8], bm[8];
#pragma unroll
    for (int nt = 0; nt < 8; ++nt) { gm[nt] = g[nt * 16 + ch]; bm[nt] = bln[nt * 16 + ch]; }

#pragma unroll
    for (int r = 0; r < 4; ++r) {
        float s = 0.f, ss = 0.f;
#pragma unroll
        for (int nt = 0; nt < 8; ++nt) { float v = fmaxf(macc[nt][r], 0.f); s += v; ss += v * v; }
#pragma unroll
        for (int m = 1; m < 16; m <<= 1) { s += __shfl_xor(s, m, 64); ss += __shfl_xor(ss, m, 64); }
        float mu = s * (1.0f / EMB);
        float rstd = rsqrtf(ss * (1.0f / EMB) - mu * mu + 1e-5f);
        int row = m0 + rbase + sub * 4 + r;
        if (row < Nrows) {
#pragma unroll
            for (int nt = 0; nt < 8; ++nt) {
                float v = fmaxf(macc[nt][r], 0.f);
                float o = (v - mu) * rstd * gm[nt] + bm[nt];
                float hv = bf2f(Asm[rbase + sub * 4 + r][nt * 16 + ch]);
                out[(size_t)row * EMB + nt * 16 + ch] = o + hv;
            }
        }
    }
}

// ---------------------------------------------------------------------------
extern "C" void kernel_launch(void* const* d_in, const int* in_sizes, int n_in,
                              void* d_out, int out_size, void* d_ws, size_t ws_size,
                              hipStream_t stream) {
    const float* variable_emb   = (const float*)d_in[0];
    const float* edge_emb       = (const float*)d_in[1];
    const float* constraint_emb = (const float*)d_in[2];
    const int*   e_u            = (const int*)d_in[3];
    const int*   e_v            = (const int*)d_in[4];
    const float* W_left  = (const float*)d_in[5];
    const float* b_left  = (const float*)d_in[6];
    const float* W_edge  = (const float*)d_in[7];
    const float* W_right = (const float*)d_in[8];
    const float* W_join  = (const float*)d_in[9];
    const float* b_join  = (const float*)d_in[10];
    const float* W_merge = (const float*)d_in[11];
    const float* b_merge = (const float*)d_in[12];
    const float* g_var   = (const float*)d_in[13];
    const float* b_var   = (const float*)d_in[14];
    const float* g_edge  = (const float*)d_in[15];
    const float* b_edge  = (const float*)d_in[16];
    const float* g_con   = (const float*)d_in[17];
    const float* b_con   = (const float*)d_in[18];
    const float* g_join_ln = (const float*)d_in[19];
    const float* b_join_ln = (const float*)d_in[20];
    const float* g_joint   = (const float*)d_in[21];
    const float* b_joint   = (const float*)d_in[22];
    const float* g_merge   = (const float*)d_in[23];
    const float* b_merge_ln = (const float*)d_in[24];

    char* ws = (char*)d_ws;
    u16* wtl = (u16*)ws; ws += 128 * 128 * 2;
    u16* wte = (u16*)ws; ws += 128 * 128 * 2;
    u16* wtr = (u16*)ws; ws += 128 * 128 * 2;
    u16* wtj = (u16*)ws; ws += 128 * 128 * 2;
    u16* wtm = (u16*)ws; ws += 256 * 128 * 2;
    u16* v_t = (u16*)ws; ws += (size_t)NU_ * EMB * 2;
    u16* c_t = (u16*)ws; ws += (size_t)NV_ * EMB * 2;

    float* out_f   = (float*)d_out;
    float* new_var = out_f;                       // [NU*128]
    float* new_con = out_f + (size_t)NU_ * EMB;   // [NV*128]
    // segment-sum accumulator aliases the new_var region (written last;
    // merge_kernel reads/writes only its own rows, so aliasing is safe)
    float* agg = out_f;

    const int gb_v = (NU_ + 63) / 64;
    const int gb_c = (NV_ + 63) / 64;
    const int gb_e = (NE_ + 63) / 64;

    convert_weights_kernel<<<5, 256, 0, stream>>>(W_left, W_edge, W_right, W_join, W_merge,
                                                  wtl, wte, wtr, wtj, wtm);
    // v_t = LN(var)@W_left + b_left  (reused by both passes)
    ln_linear_kernel<<<gb_v, 256, 0, stream>>>(variable_emb, NU_, g_var, b_var, wtl, b_left, v_t);
    // pass 1: c_t = LN(con)@W_right
    ln_linear_kernel<<<gb_c, 256, 0, stream>>>(constraint_emb, NV_, g_con, b_con, wtr, nullptr, c_t);
    hipMemsetAsync(agg, 0, (size_t)NV_ * EMB * sizeof(float), stream);
    join_scatter_kernel<<<gb_e, 256, 0, stream>>>(edge_emb, v_t, c_t, e_u, e_v, e_v,
                                                  g_edge, b_edge, wte,
                                                  g_join_ln, b_join_ln, wtj, b_join,
                                                  g_joint, b_joint, agg);
    merge_kernel<<<gb_c, 256, 0, stream>>>(c_t, agg, NV_, wtm, b_merge, g_merge, b_merge_ln, new_con);

    // pass 2: c_t = LN(new_con)@W_right
    ln_linear_kernel<<<gb_c, 256, 0, stream>>>(new_con, NV_, g_con, b_con, wtr, nullptr, c_t);
    hipMemsetAsync(agg, 0, (size_t)NU_ * EMB * sizeof(float), stream);
    join_scatter_kernel<<<gb_e, 256, 0, stream>>>(edge_emb, v_t, c_t, e_u, e_v, e_u,
                                                  g_edge, b_edge, wte,
                                                  g_join_ln, b_join_ln, wtj, b_join,
                                                  g_joint, b_joint, agg);
    merge_kernel<<<gb_v, 256, 0, stream>>>(v_t, agg, NU_, wtm, b_merge, g_merge, b_merge_ln, new_var);
}

// Round 4
// 1202.382 us; speedup vs baseline: 1.1407x; 1.1407x over previous
//
#include <hip/hip_runtime.h>
#include <hip/hip_bf16.h>

#define NU_ 100000
#define NV_ 50000
#define NE_ 500000
#define EMB 128

typedef unsigned short u16;
typedef unsigned int u32;
typedef __attribute__((ext_vector_type(8))) short short8x;
typedef __attribute__((ext_vector_type(4))) float f32x4;

__device__ __forceinline__ float bf2f(u16 u) {
    union { u32 i; float f; } c; c.i = ((u32)u) << 16; return c.f;
}
__device__ __forceinline__ u16 f2bf(float f) {
    union { float f; u32 i; } c; c.f = f;
    u32 r = c.i + 0x7fffu + ((c.i >> 16) & 1u);
    return (u16)(r >> 16);
}

// R2/R3 post-mortem: keep __syncthreads(); all new kernels below are literal
// fissions of the R1-validated join_scatter_kernel at the Esm boundary.

// ---------------------------------------------------------------------------
// Kernel 0: convert weights fp32 [K][128] -> bf16 transposed [128][K]
// ---------------------------------------------------------------------------
__global__ void convert_weights_kernel(
    const float* __restrict__ Wl, const float* __restrict__ We,
    const float* __restrict__ Wr, const float* __restrict__ Wj,
    const float* __restrict__ Wm,
    u16* __restrict__ wtl, u16* __restrict__ wte, u16* __restrict__ wtr,
    u16* __restrict__ wtj, u16* __restrict__ wtm)
{
    int b = blockIdx.x;
    const float* src; u16* dst; int K;
    if (b == 0)      { src = Wl; dst = wtl; K = 128; }
    else if (b == 1) { src = We; dst = wte; K = 128; }
    else if (b == 2) { src = Wr; dst = wtr; K = 128; }
    else if (b == 3) { src = Wj; dst = wtj; K = 128; }
    else             { src = Wm; dst = wtm; K = 256; }
    int total = K * 128;
    for (int i = threadIdx.x; i < total; i += blockDim.x) {
        int n = i / K, k = i - n * K;
        dst[i] = f2bf(src[(size_t)k * 128 + n]);   // Wt[n][k] = W[k][n]
    }
}

// ---------------------------------------------------------------------------
// Kernel 1 (verbatim R1): Y_bf16[N,128] = LN(X_f32; g,b) @ Wt (+bias)
// ---------------------------------------------------------------------------
__global__ __launch_bounds__(256) void ln_linear_kernel(
    const float* __restrict__ X, int Nrows,
    const float* __restrict__ g, const float* __restrict__ b,
    const u16* __restrict__ Wt, const float* __restrict__ bias,
    u16* __restrict__ Y)
{
    __shared__ __align__(16) u16 Asm[64][136];
    const int lane = threadIdx.x & 63, wv = threadIdx.x >> 6;
    const int ch = lane & 15, sub = lane >> 4;
    const int m0 = blockIdx.x * 64;
    const int rbase = wv * 16;

    float gv[8], bv[8];
#pragma unroll
    for (int j = 0; j < 8; ++j) { gv[j] = g[ch * 8 + j]; bv[j] = b[ch * 8 + j]; }

    for (int it = 0; it < 4; ++it) {
        int rl = rbase + it * 4 + sub;
        int row = m0 + rl;
        int rowc = row < Nrows ? row : Nrows - 1;
        const float* xr = X + (size_t)rowc * EMB + ch * 8;
        float4 a0 = *(const float4*)xr;
        float4 a1 = *(const float4*)(xr + 4);
        float x[8] = {a0.x, a0.y, a0.z, a0.w, a1.x, a1.y, a1.z, a1.w};
        float s = 0.f, ss = 0.f;
#pragma unroll
        for (int j = 0; j < 8; ++j) { s += x[j]; ss += x[j] * x[j]; }
#pragma unroll
        for (int m = 1; m < 16; m <<= 1) { s += __shfl_xor(s, m, 64); ss += __shfl_xor(ss, m, 64); }
        float mu = s * (1.0f / EMB);
        float rstd = rsqrtf(ss * (1.0f / EMB) - mu * mu + 1e-5f);
        u16 o[8];
#pragma unroll
        for (int j = 0; j < 8; ++j) o[j] = f2bf((x[j] - mu) * rstd * gv[j] + bv[j]);
        uint4 pk;
        pk.x = (u32)o[0] | ((u32)o[1] << 16);
        pk.y = (u32)o[2] | ((u32)o[3] << 16);
        pk.z = (u32)o[4] | ((u32)o[5] << 16);
        pk.w = (u32)o[6] | ((u32)o[7] << 16);
        *(uint4*)&Asm[rl][ch * 8] = pk;
    }
    __syncthreads();

    short8x afr[4];
#pragma unroll
    for (int kt = 0; kt < 4; ++kt)
        afr[kt] = *(const short8x*)&Asm[rbase + ch][kt * 32 + sub * 8];

#pragma unroll
    for (int nt = 0; nt < 8; ++nt) {
        float bz = bias ? bias[nt * 16 + ch] : 0.f;
        f32x4 acc = {bz, bz, bz, bz};
#pragma unroll
        for (int kt = 0; kt < 4; ++kt) {
            short8x bfr = *(const short8x*)(Wt + (size_t)(nt * 16 + ch) * 128 + kt * 32 + sub * 8);
            acc = __builtin_amdgcn_mfma_f32_16x16x32_bf16(afr[kt], bfr, acc, 0, 0, 0);
        }
#pragma unroll
        for (int r = 0; r < 4; ++r) {
            int row = m0 + rbase + sub * 4 + r;
            if (row < Nrows) Y[(size_t)row * EMB + nt * 16 + ch] = f2bf(acc[r]);
        }
    }
}

// ---------------------------------------------------------------------------
// et_kernel: FISSION of R1 join (phase A + MFMA1), storing e_t to GLOBAL
// instead of Esm. Code verbatim from the validated R1 join_scatter_kernel.
// ---------------------------------------------------------------------------
__global__ __launch_bounds__(256) void et_kernel(
    const float* __restrict__ Xe,
    const float* __restrict__ g_e, const float* __restrict__ b_e,
    const u16* __restrict__ Wt_e,
    u16* __restrict__ e_t)
{
    __shared__ __align__(16) u16 Asm[64][136];
    const int lane = threadIdx.x & 63, wv = threadIdx.x >> 6;
    const int ch = lane & 15, sub = lane >> 4;
    const int m0 = blockIdx.x * 64;
    const int rbase = wv * 16;

    float gev[8], bev[8];
#pragma unroll
    for (int j = 0; j < 8; ++j) { gev[j] = g_e[ch * 8 + j]; bev[j] = b_e[ch * 8 + j]; }

    for (int it = 0; it < 4; ++it) {
        int rl = rbase + it * 4 + sub;
        int edge = m0 + rl;
        int ec = edge < NE_ ? edge : NE_ - 1;
        const float* xr = Xe + (size_t)ec * EMB + ch * 8;
        float4 a0 = *(const float4*)xr;
        float4 a1 = *(const float4*)(xr + 4);
        float x[8] = {a0.x, a0.y, a0.z, a0.w, a1.x, a1.y, a1.z, a1.w};
        float s = 0.f, ss = 0.f;
#pragma unroll
        for (int j = 0; j < 8; ++j) { s += x[j]; ss += x[j] * x[j]; }
#pragma unroll
        for (int m = 1; m < 16; m <<= 1) { s += __shfl_xor(s, m, 64); ss += __shfl_xor(ss, m, 64); }
        float mu = s * (1.0f / EMB);
        float rstd = rsqrtf(ss * (1.0f / EMB) - mu * mu + 1e-5f);
        u16 o[8];
#pragma unroll
        for (int j = 0; j < 8; ++j) o[j] = f2bf((x[j] - mu) * rstd * gev[j] + bev[j]);
        uint4 pk;
        pk.x = (u32)o[0] | ((u32)o[1] << 16);
        pk.y = (u32)o[2] | ((u32)o[3] << 16);
        pk.z = (u32)o[4] | ((u32)o[5] << 16);
        pk.w = (u32)o[6] | ((u32)o[7] << 16);
        *(uint4*)&Asm[rl][ch * 8] = pk;
    }
    __syncthreads();

    short8x afr[4];
#pragma unroll
    for (int kt = 0; kt < 4; ++kt)
        afr[kt] = *(const short8x*)&Asm[rbase + ch][kt * 32 + sub * 8];
#pragma unroll
    for (int nt = 0; nt < 8; ++nt) {
        f32x4 acc = {0.f, 0.f, 0.f, 0.f};
#pragma unroll
        for (int kt = 0; kt < 4; ++kt) {
            short8x bfr = *(const short8x*)(Wt_e + (size_t)(nt * 16 + ch) * 128 + kt * 32 + sub * 8);
            acc = __builtin_amdgcn_mfma_f32_16x16x32_bf16(afr[kt], bfr, acc, 0, 0, 0);
        }
#pragma unroll
        for (int r = 0; r < 4; ++r) {
            int edge = m0 + rbase + sub * 4 + r;
            if (edge < NE_) e_t[(size_t)edge * EMB + nt * 16 + ch] = f2bf(acc[r]);
        }
    }
}

// ---------------------------------------------------------------------------
// join_pre2_kernel: FISSION of R1 join — phase A/MFMA1 replaced by a global
// uint4 copy of e_t into Esm. Phase C, MFMA2, epilogue, barriers verbatim R1.
// ---------------------------------------------------------------------------
__global__ __launch_bounds__(256) void join_pre2_kernel(
    const u16* __restrict__ e_t,
    const u16* __restrict__ v_t, const u16* __restrict__ c_t,
    const int* __restrict__ e_u, const int* __restrict__ e_v,
    const int* __restrict__ seg,
    const float* __restrict__ g1, const float* __restrict__ b1,
    const u16* __restrict__ Wt_j, const float* __restrict__ bias_j,
    const float* __restrict__ g2, const float* __restrict__ b2,
    float* __restrict__ agg)
{
    __shared__ __align__(16) u16 Asm[64][136];
    __shared__ __align__(16) u16 Esm[64][136];
    const int lane = threadIdx.x & 63, wv = threadIdx.x >> 6;
    const int ch = lane & 15, sub = lane >> 4;
    const int m0 = blockIdx.x * 64;
    const int rbase = wv * 16;

    // Esm <- e_t (global), replacing R1's in-kernel recompute
    for (int it = 0; it < 4; ++it) {
        int rl = rbase + it * 4 + sub;
        int edge = m0 + rl;
        int ec = edge < NE_ ? edge : NE_ - 1;
        *(uint4*)&Esm[rl][ch * 8] = *(const uint4*)(e_t + (size_t)ec * EMB + ch * 8);
    }
    __syncthreads();

    float g1v[8], b1v[8];
#pragma unroll
    for (int j = 0; j < 8; ++j) { g1v[j] = g1[ch * 8 + j]; b1v[j] = b1[ch * 8 + j]; }
    for (int it = 0; it < 4; ++it) {
        int rl = rbase + it * 4 + sub;
        int edge = m0 + rl;
        int ec = edge < NE_ ? edge : NE_ - 1;
        int u = e_u[ec], vv = e_v[ec];
        uint4 vq = *(const uint4*)(v_t + (size_t)u * EMB + ch * 8);
        uint4 cq = *(const uint4*)(c_t + (size_t)vv * EMB + ch * 8);
        uint4 eq = *(const uint4*)&Esm[rl][ch * 8];
        u32 vw[4] = {vq.x, vq.y, vq.z, vq.w};
        u32 cw[4] = {cq.x, cq.y, cq.z, cq.w};
        u32 ew[4] = {eq.x, eq.y, eq.z, eq.w};
        float x[8];
#pragma unroll
        for (int j = 0; j < 4; ++j) {
            float v0 = bf2f((u16)(vw[j] & 0xffff)) + bf2f((u16)(cw[j] & 0xffff)) + bf2f((u16)(ew[j] & 0xffff));
            float v1 = bf2f((u16)(vw[j] >> 16)) + bf2f((u16)(cw[j] >> 16)) + bf2f((u16)(ew[j] >> 16));
            x[2 * j] = fmaxf(v0, 0.f);
            x[2 * j + 1] = fmaxf(v1, 0.f);
        }
        float s = 0.f, ss = 0.f;
#pragma unroll
        for (int j = 0; j < 8; ++j) { s += x[j]; ss += x[j] * x[j]; }
#pragma unroll
        for (int m = 1; m < 16; m <<= 1) { s += __shfl_xor(s, m, 64); ss += __shfl_xor(ss, m, 64); }
        float mu = s * (1.0f / EMB);
        float rstd = rsqrtf(ss * (1.0f / EMB) - mu * mu + 1e-5f);
        u16 o[8];
#pragma unroll
        for (int j = 0; j < 8; ++j) o[j] = f2bf((x[j] - mu) * rstd * g1v[j] + b1v[j]);
        uint4 pk;
        pk.x = (u32)o[0] | ((u32)o[1] << 16);
        pk.y = (u32)o[2] | ((u32)o[3] << 16);
        pk.z = (u32)o[4] | ((u32)o[5] << 16);
        pk.w = (u32)o[6] | ((u32)o[7] << 16);
        *(uint4*)&Asm[rl][ch * 8] = pk;
    }
    __syncthreads();

    short8x afr[4];
#pragma unroll
    for (int kt = 0; kt < 4; ++kt)
        afr[kt] = *(const short8x*)&Asm[rbase + ch][kt * 32 + sub * 8];

    f32x4 jacc[8];
#pragma unroll
    for (int nt = 0; nt < 8; ++nt) {
        float bz = bias_j[nt * 16 + ch];
        f32x4 acc = {bz, bz, bz, bz};
#pragma unroll
        for (int kt = 0; kt < 4; ++kt) {
            short8x bfr = *(const short8x*)(Wt_j + (size_t)(nt * 16 + ch) * 128 + kt * 32 + sub * 8);
            acc = __builtin_amdgcn_mfma_f32_16x16x32_bf16(afr[kt], bfr, acc, 0, 0, 0);
        }
        jacc[nt] = acc;
    }

    float g2v[8], b2v[8];
#pragma unroll
    for (int nt = 0; nt < 8; ++nt) { g2v[nt] = g2[nt * 16 + ch]; b2v[nt] = b2[nt * 16 + ch]; }

#pragma unroll
    for (int r = 0; r < 4; ++r) {
        float s = 0.f, ss = 0.f;
#pragma unroll
        for (int nt = 0; nt < 8; ++nt) { float v = jacc[nt][r]; s += v; ss += v * v; }
#pragma unroll
        for (int m = 1; m < 16; m <<= 1) { s += __shfl_xor(s, m, 64); ss += __shfl_xor(ss, m, 64); }
        float mu = s * (1.0f / EMB);
        float rstd = rsqrtf(ss * (1.0f / EMB) - mu * mu + 1e-5f);
        int edge = m0 + rbase + sub * 4 + r;
        if (edge < NE_) {
            int sg = seg[edge];
            float* dst = agg + (size_t)sg * EMB + ch;
#pragma unroll
            for (int nt = 0; nt < 8; ++nt) {
                float val = (jacc[nt][r] - mu) * rstd * g2v[nt] + b2v[nt];
                atomicAdd(dst + nt * 16, val);
            }
        }
    }
}

// ---------------------------------------------------------------------------
// Kernel 2 (v1 fallback, verbatim R1): recomputes e_t in-kernel.
// ---------------------------------------------------------------------------
__global__ __launch_bounds__(256) void join_scatter_kernel(
    const float* __restrict__ Xe,
    const u16* __restrict__ v_t, const u16* __restrict__ c_t,
    const int* __restrict__ e_u, const int* __restrict__ e_v,
    const int* __restrict__ seg,
    const float* __restrict__ g_e, const float* __restrict__ b_e,
    const u16* __restrict__ Wt_e,
    const float* __restrict__ g1, const float* __restrict__ b1,
    const u16* __restrict__ Wt_j, const float* __restrict__ bias_j,
    const float* __restrict__ g2, const float* __restrict__ b2,
    float* __restrict__ agg)
{
    __shared__ __align__(16) u16 Asm[64][136];
    __shared__ __align__(16) u16 Esm[64][136];
    const int lane = threadIdx.x & 63, wv = threadIdx.x >> 6;
    const int ch = lane & 15, sub = lane >> 4;
    const int m0 = blockIdx.x * 64;
    const int rbase = wv * 16;

    float gev[8], bev[8];
#pragma unroll
    for (int j = 0; j < 8; ++j) { gev[j] = g_e[ch * 8 + j]; bev[j] = b_e[ch * 8 + j]; }

    for (int it = 0; it < 4; ++it) {
        int rl = rbase + it * 4 + sub;
        int edge = m0 + rl;
        int ec = edge < NE_ ? edge : NE_ - 1;
        const float* xr = Xe + (size_t)ec * EMB + ch * 8;
        float4 a0 = *(const float4*)xr;
        float4 a1 = *(const float4*)(xr + 4);
        float x[8] = {a0.x, a0.y, a0.z, a0.w, a1.x, a1.y, a1.z, a1.w};
        float s = 0.f, ss = 0.f;
#pragma unroll
        for (int j = 0; j < 8; ++j) { s += x[j]; ss += x[j] * x[j]; }
#pragma unroll
        for (int m = 1; m < 16; m <<= 1) { s += __shfl_xor(s, m, 64); ss += __shfl_xor(ss, m, 64); }
        float mu = s * (1.0f / EMB);
        float rstd = rsqrtf(ss * (1.0f / EMB) - mu * mu + 1e-5f);
        u16 o[8];
#pragma unroll
        for (int j = 0; j < 8; ++j) o[j] = f2bf((x[j] - mu) * rstd * gev[j] + bev[j]);
        uint4 pk;
        pk.x = (u32)o[0] | ((u32)o[1] << 16);
        pk.y = (u32)o[2] | ((u32)o[3] << 16);
        pk.z = (u32)o[4] | ((u32)o[5] << 16);
        pk.w = (u32)o[6] | ((u32)o[7] << 16);
        *(uint4*)&Asm[rl][ch * 8] = pk;
    }
    __syncthreads();

    {
        short8x afr[4];
#pragma unroll
        for (int kt = 0; kt < 4; ++kt)
            afr[kt] = *(const short8x*)&Asm[rbase + ch][kt * 32 + sub * 8];
#pragma unroll
        for (int nt = 0; nt < 8; ++nt) {
            f32x4 acc = {0.f, 0.f, 0.f, 0.f};
#pragma unroll
            for (int kt = 0; kt < 4; ++kt) {
                short8x bfr = *(const short8x*)(Wt_e + (size_t)(nt * 16 + ch) * 128 + kt * 32 + sub * 8);
                acc = __builtin_amdgcn_mfma_f32_16x16x32_bf16(afr[kt], bfr, acc, 0, 0, 0);
            }
#pragma unroll
            for (int r = 0; r < 4; ++r)
                Esm[rbase + sub * 4 + r][nt * 16 + ch] = f2bf(acc[r]);
        }
    }
    __syncthreads();

    float g1v[8], b1v[8];
#pragma unroll
    for (int j = 0; j < 8; ++j) { g1v[j] = g1[ch * 8 + j]; b1v[j] = b1[ch * 8 + j]; }
    for (int it = 0; it < 4; ++it) {
        int rl = rbase + it * 4 + sub;
        int edge = m0 + rl;
        int ec = edge < NE_ ? edge : NE_ - 1;
        int u = e_u[ec], vv = e_v[ec];
        uint4 vq = *(const uint4*)(v_t + (size_t)u * EMB + ch * 8);
        uint4 cq = *(const uint4*)(c_t + (size_t)vv * EMB + ch * 8);
        uint4 eq = *(const uint4*)&Esm[rl][ch * 8];
        u32 vw[4] = {vq.x, vq.y, vq.z, vq.w};
        u32 cw[4] = {cq.x, cq.y, cq.z, cq.w};
        u32 ew[4] = {eq.x, eq.y, eq.z, eq.w};
        float x[8];
#pragma unroll
        for (int j = 0; j < 4; ++j) {
            float v0 = bf2f((u16)(vw[j] & 0xffff)) + bf2f((u16)(cw[j] & 0xffff)) + bf2f((u16)(ew[j] & 0xffff));
            float v1 = bf2f((u16)(vw[j] >> 16)) + bf2f((u16)(cw[j] >> 16)) + bf2f((u16)(ew[j] >> 16));
            x[2 * j] = fmaxf(v0, 0.f);
            x[2 * j + 1] = fmaxf(v1, 0.f);
        }
        float s = 0.f, ss = 0.f;
#pragma unroll
        for (int j = 0; j < 8; ++j) { s += x[j]; ss += x[j] * x[j]; }
#pragma unroll
        for (int m = 1; m < 16; m <<= 1) { s += __shfl_xor(s, m, 64); ss += __shfl_xor(ss, m, 64); }
        float mu = s * (1.0f / EMB);
        float rstd = rsqrtf(ss * (1.0f / EMB) - mu * mu + 1e-5f);
        u16 o[8];
#pragma unroll
        for (int j = 0; j < 8; ++j) o[j] = f2bf((x[j] - mu) * rstd * g1v[j] + b1v[j]);
        uint4 pk;
        pk.x = (u32)o[0] | ((u32)o[1] << 16);
        pk.y = (u32)o[2] | ((u32)o[3] << 16);
        pk.z = (u32)o[4] | ((u32)o[5] << 16);
        pk.w = (u32)o[6] | ((u32)o[7] << 16);
        *(uint4*)&Asm[rl][ch * 8] = pk;
    }
    __syncthreads();

    short8x afr[4];
#pragma unroll
    for (int kt = 0; kt < 4; ++kt)
        afr[kt] = *(const short8x*)&Asm[rbase + ch][kt * 32 + sub * 8];

    f32x4 jacc[8];
#pragma unroll
    for (int nt = 0; nt < 8; ++nt) {
        float bz = bias_j[nt * 16 + ch];
        f32x4 acc = {bz, bz, bz, bz};
#pragma unroll
        for (int kt = 0; kt < 4; ++kt) {
            short8x bfr = *(const short8x*)(Wt_j + (size_t)(nt * 16 + ch) * 128 + kt * 32 + sub * 8);
            acc = __builtin_amdgcn_mfma_f32_16x16x32_bf16(afr[kt], bfr, acc, 0, 0, 0);
        }
        jacc[nt] = acc;
    }

    float g2v[8], b2v[8];
#pragma unroll
    for (int nt = 0; nt < 8; ++nt) { g2v[nt] = g2[nt * 16 + ch]; b2v[nt] = b2[nt * 16 + ch]; }

#pragma unroll
    for (int r = 0; r < 4; ++r) {
        float s = 0.f, ss = 0.f;
#pragma unroll
        for (int nt = 0; nt < 8; ++nt) { float v = jacc[nt][r]; s += v; ss += v * v; }
#pragma unroll
        for (int m = 1; m < 16; m <<= 1) { s += __shfl_xor(s, m, 64); ss += __shfl_xor(ss, m, 64); }
        float mu = s * (1.0f / EMB);
        float rstd = rsqrtf(ss * (1.0f / EMB) - mu * mu + 1e-5f);
        int edge = m0 + rbase + sub * 4 + r;
        if (edge < NE_) {
            int sg = seg[edge];
            float* dst = agg + (size_t)sg * EMB + ch;
#pragma unroll
            for (int nt = 0; nt < 8; ++nt) {
                float val = (jacc[nt][r] - mu) * rstd * g2v[nt] + b2v[nt];
                atomicAdd(dst + nt * 16, val);
            }
        }
    }
}

// ---------------------------------------------------------------------------
// Kernel 3 (verbatim R1): out = h + LN(relu([h, agg] @ W_merge + b_merge))
// ---------------------------------------------------------------------------
__global__ __launch_bounds__(256) void merge_kernel(
    const u16* __restrict__ h, const float* __restrict__ agg, int Nrows,
    const u16* __restrict__ Wt_m,   // [128][256]
    const float* __restrict__ bias, const float* __restrict__ g,
    const float* __restrict__ bln,
    float* __restrict__ out)
{
    __shared__ __align__(16) u16 Asm[64][264];
    const int lane = threadIdx.x & 63, wv = threadIdx.x >> 6;
    const int ch = lane & 15, sub = lane >> 4;
    const int m0 = blockIdx.x * 64;
    const int rbase = wv * 16;

    for (int it = 0; it < 4; ++it) {
        int rl = rbase + it * 4 + sub;
        int row = m0 + rl;
        int rowc = row < Nrows ? row : Nrows - 1;
        uint4 hq = *(const uint4*)(h + (size_t)rowc * EMB + ch * 8);
        *(uint4*)&Asm[rl][ch * 8] = hq;
        const float* ar = agg + (size_t)rowc * EMB + ch * 8;
        float4 a0 = *(const float4*)ar;
        float4 a1 = *(const float4*)(ar + 4);
        float x[8] = {a0.x, a0.y, a0.z, a0.w, a1.x, a1.y, a1.z, a1.w};
        u16 o[8];
#pragma unroll
        for (int j = 0; j < 8; ++j) o[j] = f2bf(x[j]);
        uint4 pk;
        pk.x = (u32)o[0] | ((u32)o[1] << 16);
        pk.y = (u32)o[2] | ((u32)o[3] << 16);
        pk.z = (u32)o[4] | ((u32)o[5] << 16);
        pk.w = (u32)o[6] | ((u32)o[7] << 16);
        *(uint4*)&Asm[rl][128 + ch * 8] = pk;
    }
    __syncthreads();

    short8x afr[8];
#pragma unroll
    for (int kt = 0; kt < 8; ++kt)
        afr[kt] = *(const short8x*)&Asm[rbase + ch][kt * 32 + sub * 8];

    f32x4 macc[8];
#pragma unroll
    for (int nt = 0; nt < 8; ++nt) {
        float bz = bias[nt * 16 + ch];
        f32x4 acc = {bz, bz, bz, bz};
#pragma unroll
        for (int kt = 0; kt < 8; ++kt) {
            short8x bfr = *(const short8x*)(Wt_m + (size_t)(nt * 16 + ch) * 256 + kt * 32 + sub * 8);
            acc = __builtin_amdgcn_mfma_f32_16x16x32_bf16(afr[kt], bfr, acc, 0, 0, 0);
        }
        macc[nt] = acc;
    }

    float gm[8], bm[8];
#pragma unroll
    for (int nt = 0; nt < 8; ++nt) { gm[nt] = g[nt * 16 + ch]; bm[nt] = bln[nt * 16 + ch]; }

#pragma unroll
    for (int r = 0; r < 4; ++r) {
        float s = 0.f, ss = 0.f;
#pragma unroll
        for (int nt = 0; nt < 8; ++nt) { float v = fmaxf(macc[nt][r], 0.f); s += v; ss += v * v; }
#pragma unroll
        for (int m = 1; m < 16; m <<= 1) { s += __shfl_xor(s, m, 64); ss += __shfl_xor(ss, m, 64); }
        float mu = s * (1.0f / EMB);
        float rstd = rsqrtf(ss * (1.0f / EMB) - mu * mu + 1e-5f);
        int row = m0 + rbase + sub * 4 + r;
        if (row < Nrows) {
#pragma unroll
            for (int nt = 0; nt < 8; ++nt) {
                float v = fmaxf(macc[nt][r], 0.f);
                float o = (v - mu) * rstd * gm[nt] + bm[nt];
                float hv = bf2f(Asm[rbase + sub * 4 + r][nt * 16 + ch]);
                out[(size_t)row * EMB + nt * 16 + ch] = o + hv;
            }
        }
    }
}

// ---------------------------------------------------------------------------
extern "C" void kernel_launch(void* const* d_in, const int* in_sizes, int n_in,
                              void* d_out, int out_size, void* d_ws, size_t ws_size,
                              hipStream_t stream) {
    const float* variable_emb   = (const float*)d_in[0];
    const float* edge_emb       = (const float*)d_in[1];
    const float* constraint_emb = (const float*)d_in[2];
    const int*   e_u            = (const int*)d_in[3];
    const int*   e_v            = (const int*)d_in[4];
    const float* W_left  = (const float*)d_in[5];
    const float* b_left  = (const float*)d_in[6];
    const float* W_edge  = (const float*)d_in[7];
    const float* W_right = (const float*)d_in[8];
    const float* W_join  = (const float*)d_in[9];
    const float* b_join  = (const float*)d_in[10];
    const float* W_merge = (const float*)d_in[11];
    const float* b_merge = (const float*)d_in[12];
    const float* g_var   = (const float*)d_in[13];
    const float* b_var   = (const float*)d_in[14];
    const float* g_edge  = (const float*)d_in[15];
    const float* b_edge  = (const float*)d_in[16];
    const float* g_con   = (const float*)d_in[17];
    const float* b_con   = (const float*)d_in[18];
    const float* g_join_ln = (const float*)d_in[19];
    const float* b_join_ln = (const float*)d_in[20];
    const float* g_joint   = (const float*)d_in[21];
    const float* b_joint   = (const float*)d_in[22];
    const float* g_merge   = (const float*)d_in[23];
    const float* b_merge_ln = (const float*)d_in[24];

    char* ws = (char*)d_ws;
    u16* wtl = (u16*)ws; ws += 128 * 128 * 2;
    u16* wte = (u16*)ws; ws += 128 * 128 * 2;
    u16* wtr = (u16*)ws; ws += 128 * 128 * 2;
    u16* wtj = (u16*)ws; ws += 128 * 128 * 2;
    u16* wtm = (u16*)ws; ws += 256 * 128 * 2;
    u16* v_t = (u16*)ws; ws += (size_t)NU_ * EMB * 2;
    u16* c_t = (u16*)ws; ws += (size_t)NV_ * EMB * 2;
    u16* e_t = (u16*)ws; ws += (size_t)NE_ * EMB * 2;
    size_t ws_needed = (size_t)(ws - (char*)d_ws);
    const bool have_et = ws_size >= ws_needed;   // constant across calls

    float* out_f   = (float*)d_out;
    float* new_var = out_f;                       // [NU*128]
    float* new_con = out_f + (size_t)NU_ * EMB;   // [NV*128]
    float* agg = out_f;  // aliases new_var region; consumed before overwrite

    const int gb_v = (NU_ + 63) / 64;
    const int gb_c = (NV_ + 63) / 64;
    const int gb_e = (NE_ + 63) / 64;

    convert_weights_kernel<<<5, 256, 0, stream>>>(W_left, W_edge, W_right, W_join, W_merge,
                                                  wtl, wte, wtr, wtj, wtm);
    ln_linear_kernel<<<gb_v, 256, 0, stream>>>(variable_emb, NU_, g_var, b_var, wtl, b_left, v_t);
    ln_linear_kernel<<<gb_c, 256, 0, stream>>>(constraint_emb, NV_, g_con, b_con, wtr, nullptr, c_t);

    if (have_et) {
        et_kernel<<<gb_e, 256, 0, stream>>>(edge_emb, g_edge, b_edge, wte, e_t);

        hipMemsetAsync(agg, 0, (size_t)NV_ * EMB * sizeof(float), stream);
        join_pre2_kernel<<<gb_e, 256, 0, stream>>>(e_t, v_t, c_t, e_u, e_v, e_v,
                                                   g_join_ln, b_join_ln, wtj, b_join,
                                                   g_joint, b_joint, agg);
        merge_kernel<<<gb_c, 256, 0, stream>>>(c_t, agg, NV_, wtm, b_merge, g_merge, b_merge_ln, new_con);

        ln_linear_kernel<<<gb_c, 256, 0, stream>>>(new_con, NV_, g_con, b_con, wtr, nullptr, c_t);
        hipMemsetAsync(agg, 0, (size_t)NU_ * EMB * sizeof(float), stream);
        join_pre2_kernel<<<gb_e, 256, 0, stream>>>(e_t, v_t, c_t, e_u, e_v, e_u,
                                                   g_join_ln, b_join_ln, wtj, b_join,
                                                   g_joint, b_joint, agg);
        merge_kernel<<<gb_v, 256, 0, stream>>>(v_t, agg, NU_, wtm, b_merge, g_merge, b_merge_ln, new_var);
    } else {
        hipMemsetAsync(agg, 0, (size_t)NV_ * EMB * sizeof(float), stream);
        join_scatter_kernel<<<gb_e, 256, 0, stream>>>(edge_emb, v_t, c_t, e_u, e_v, e_v,
                                                      g_edge, b_edge, wte,
                                                      g_join_ln, b_join_ln, wtj, b_join,
                                                      g_joint, b_joint, agg);
        merge_kernel<<<gb_c, 256, 0, stream>>>(c_t, agg, NV_, wtm, b_merge, g_merge, b_merge_ln, new_con);

        ln_linear_kernel<<<gb_c, 256, 0, stream>>>(new_con, NV_, g_con, b_con, wtr, nullptr, c_t);
        hipMemsetAsync(agg, 0, (size_t)NU_ * EMB * sizeof(float), stream);
        join_scatter_kernel<<<gb_e, 256, 0, stream>>>(edge_emb, v_t, c_t, e_u, e_v, e_u,
                                                      g_edge, b_edge, wte,
                                                      g_join_ln, b_join_ln, wtj, b_join,
                                                      g_joint, b_joint, agg);
        merge_kernel<<<gb_v, 256, 0, stream>>>(v_t, agg, NU_, wtm, b_merge, g_merge, b_merge_ln, new_var);
    }
}